// Round 2
// 260.196 us; speedup vs baseline: 1.0101x; 1.0101x over previous
//
#include <hip/hip_runtime.h>
#include <math.h>

#define DIM 4096
#define CAP 8192
#define EPS 1e-8f

// ---------------------------------------------------------------------------
// Kernel A: weighted[row] = (dot(mb[row],q) / max(||q||*||mb[row]||, eps))
//                           * importance[row] * exp(-0.001*age[row])
// Wave-per-row: 4 rows per 256-thread block, 2048 blocks. No LDS, no
// __syncthreads — pure shuffle reduction. 16 float4 loads per lane stream
// the 16 KiB row; query is L1/L2 resident.
// ---------------------------------------------------------------------------
__global__ __launch_bounds__(256) void score_kernel(
    const float* __restrict__ q,
    const float* __restrict__ mb,
    const float* __restrict__ imp,
    const float* __restrict__ age,
    float* __restrict__ weighted)
{
    const int wave = threadIdx.x >> 6;
    const int lane = threadIdx.x & 63;
    const int row  = (blockIdx.x << 2) + wave;

    const float4* __restrict__ mrow = (const float4*)(mb + (size_t)row * DIM);
    const float4* __restrict__ q4   = (const float4*)q;

    float dot = 0.f, msq = 0.f, qsq = 0.f;
    #pragma unroll 4
    for (int i = lane; i < DIM / 4; i += 64) {
        float4 m  = mrow[i];
        float4 qq = q4[i];
        dot = fmaf(m.w, qq.w, fmaf(m.z, qq.z, fmaf(m.y, qq.y, fmaf(m.x, qq.x, dot))));
        msq = fmaf(m.w, m.w,  fmaf(m.z, m.z,  fmaf(m.y, m.y,  fmaf(m.x, m.x,  msq))));
        qsq = fmaf(qq.w, qq.w, fmaf(qq.z, qq.z, fmaf(qq.y, qq.y, fmaf(qq.x, qq.x, qsq))));
    }
    #pragma unroll
    for (int off = 32; off > 0; off >>= 1) {
        dot += __shfl_down(dot, off, 64);
        msq += __shfl_down(msq, off, 64);
        qsq += __shfl_down(qsq, off, 64);
    }
    if (lane == 0) {
        float denom = fmaxf(sqrtf(qsq) * sqrtf(msq), EPS);
        weighted[row] = (dot / denom) * imp[row] * expf(-0.001f * age[row]);
    }
}

// ---------------------------------------------------------------------------
// Kernel B: top-k via tournament argmax + gather-mean. Single block, 512
// threads (8 waves). Thread t owns scores {t + 512*j : j=0..15} — stride-512
// ownership puts each lane in its own LDS bank (conflict-free) and keeps the
// running chunk-max in registers. Per selection iteration: 6-step shuffle
// reduce + 8-way combine; only the owner of the removed element rescans its
// 16 values. Lowest-index tie-break matches jax.lax.top_k.
// ---------------------------------------------------------------------------
__global__ __launch_bounds__(512) void topk_gather_kernel(
    const float* __restrict__ weighted,
    const float* __restrict__ mb,
    const int* __restrict__ topk_ptr,
    float* __restrict__ retrieved)
{
    __shared__ float wv[CAP];          // 32 KiB
    __shared__ float rv[8];
    __shared__ int   ri[8];
    __shared__ int   sidx[64];

    const int tid  = threadIdx.x;
    const int wave = tid >> 6;
    const int lane = tid & 63;

    // vectorized LDS fill (weighted is L2-hot, 32 KiB)
    {
        const float4* __restrict__ w4  = (const float4*)weighted;
        float4* __restrict__       wv4 = (float4*)wv;
        #pragma unroll
        for (int i = tid; i < CAP / 4; i += 512) wv4[i] = w4[i];
    }
    __syncthreads();

    int k = *topk_ptr;
    if (k < 1) k = 1;
    if (k > 64) k = 64;

    // initial per-thread chunk max (registers); ascending j + strict > keeps
    // the lowest index within the chunk
    float bv = -INFINITY; int bi = tid;
    #pragma unroll
    for (int j = 0; j < CAP / 512; ++j) {
        const int idx = tid + (j << 9);
        const float v = wv[idx];
        if (v > bv) { bv = v; bi = idx; }
    }

    for (int it = 0; it < k; ++it) {
        // wave shuffle argmax with global-index tie-break
        float cv = bv; int ci = bi;
        #pragma unroll
        for (int off = 32; off > 0; off >>= 1) {
            float ov = __shfl_down(cv, off, 64);
            int   oi = __shfl_down(ci, off, 64);
            if (ov > cv || (ov == cv && oi < ci)) { cv = ov; ci = oi; }
        }
        if (lane == 0) { rv[wave] = cv; ri[wave] = ci; }
        __syncthreads();
        if (tid == 0) {
            float best = rv[0]; int besti = ri[0];
            #pragma unroll
            for (int w = 1; w < 8; ++w) {
                if (rv[w] > best || (rv[w] == best && ri[w] < besti)) {
                    best = rv[w]; besti = ri[w];
                }
            }
            sidx[it] = besti;
            wv[besti] = -INFINITY;     // remove for next pass
        }
        __syncthreads();
        // only the owner of the removed element rescans its chunk. Its wave
        // peers read bv/bi via shuffle next iteration — wave lockstep orders
        // the rescan before the shuffle; cross-wave flow goes through rv/ri
        // + __syncthreads. Thread 0's next wv write is barrier-separated.
        const int gbi = sidx[it];
        if ((gbi & 511) == tid) {
            bv = -INFINITY; bi = tid;
            #pragma unroll
            for (int j = 0; j < CAP / 512; ++j) {
                const int idx = tid + (j << 9);
                const float v = wv[idx];
                if (v > bv) { bv = v; bi = idx; }
            }
        }
    }
    __syncthreads();

    // gather-mean of the k selected rows (rows are L2/L3-hot from kernel A)
    const float inv_k = 1.0f / (float)k;
    for (int i = tid; i < DIM / 4; i += 512) {
        float4 acc = make_float4(0.f, 0.f, 0.f, 0.f);
        for (int r = 0; r < k; ++r) {
            const float4 v = ((const float4*)(mb + (size_t)sidx[r] * DIM))[i];
            acc.x += v.x; acc.y += v.y; acc.z += v.z; acc.w += v.w;
        }
        acc.x *= inv_k; acc.y *= inv_k; acc.z *= inv_k; acc.w *= inv_k;
        ((float4*)retrieved)[i] = acc;
    }
}

// ---------------------------------------------------------------------------
// Kernel C: out[j] = dot(W_dec[j,:], retrieved) + b_dec[j]
// Wave-per-output: 4 outputs per 256-thread block, 1024 blocks. No LDS,
// no __syncthreads. retrieved (16 KiB) is L2-resident.
// ---------------------------------------------------------------------------
__global__ __launch_bounds__(256) void decode_kernel(
    const float* __restrict__ W,
    const float* __restrict__ b,
    const float* __restrict__ r,
    float* __restrict__ out)
{
    const int wave = threadIdx.x >> 6;
    const int lane = threadIdx.x & 63;
    const int j    = (blockIdx.x << 2) + wave;

    const float4* __restrict__ wrow = (const float4*)(W + (size_t)j * DIM);
    const float4* __restrict__ r4   = (const float4*)r;

    float acc = 0.f;
    #pragma unroll 4
    for (int i = lane; i < DIM / 4; i += 64) {
        float4 w = wrow[i];
        float4 v = r4[i];
        acc = fmaf(w.w, v.w, fmaf(w.z, v.z, fmaf(w.y, v.y, fmaf(w.x, v.x, acc))));
    }
    #pragma unroll
    for (int off = 32; off > 0; off >>= 1) acc += __shfl_down(acc, off, 64);
    if (lane == 0) out[j] = acc + b[j];
}

extern "C" void kernel_launch(void* const* d_in, const int* in_sizes, int n_in,
                              void* d_out, int out_size, void* d_ws, size_t ws_size,
                              hipStream_t stream) {
    const float* query      = (const float*)d_in[0];
    const float* memory     = (const float*)d_in[1];
    const float* importance = (const float*)d_in[2];
    const float* age        = (const float*)d_in[3];
    const float* W_dec      = (const float*)d_in[4];
    const float* b_dec      = (const float*)d_in[5];
    const int*   top_k      = (const int*)d_in[6];

    float* weighted  = (float*)d_ws;                 // CAP floats
    float* retrieved = (float*)d_ws + CAP;           // DIM floats
    float* out       = (float*)d_out;

    score_kernel<<<CAP / 4, 256, 0, stream>>>(query, memory, importance, age, weighted);
    topk_gather_kernel<<<1, 512, 0, stream>>>(weighted, memory, top_k, retrieved);
    decode_kernel<<<DIM / 4, 256, 0, stream>>>(W_dec, b_dec, retrieved, out);
}

// Round 3
// 254.693 us; speedup vs baseline: 1.0319x; 1.0216x over previous
//
#include <hip/hip_runtime.h>
#include <math.h>

#define DIM 4096
#define CAP 8192
#define EPS 1e-8f

// ---------------------------------------------------------------------------
// Kernel A: weighted[row] = (dot(mb[row],q) / max(||q||*||mb[row]||, eps))
//                           * importance[row] * exp(-0.001*age[row])
// Wave-per-row: 4 rows per 256-thread block, 2048 blocks. No LDS, no
// __syncthreads — pure shuffle reduction. Mandatory 128 MiB read, BW-bound.
// ---------------------------------------------------------------------------
__global__ __launch_bounds__(256) void score_kernel(
    const float* __restrict__ q,
    const float* __restrict__ mb,
    const float* __restrict__ imp,
    const float* __restrict__ age,
    float* __restrict__ weighted)
{
    const int wave = threadIdx.x >> 6;
    const int lane = threadIdx.x & 63;
    const int row  = (blockIdx.x << 2) + wave;

    const float4* __restrict__ mrow = (const float4*)(mb + (size_t)row * DIM);
    const float4* __restrict__ q4   = (const float4*)q;

    float dot = 0.f, msq = 0.f, qsq = 0.f;
    #pragma unroll 4
    for (int i = lane; i < DIM / 4; i += 64) {
        float4 m  = mrow[i];
        float4 qq = q4[i];
        dot = fmaf(m.w, qq.w, fmaf(m.z, qq.z, fmaf(m.y, qq.y, fmaf(m.x, qq.x, dot))));
        msq = fmaf(m.w, m.w,  fmaf(m.z, m.z,  fmaf(m.y, m.y,  fmaf(m.x, m.x,  msq))));
        qsq = fmaf(qq.w, qq.w, fmaf(qq.z, qq.z, fmaf(qq.y, qq.y, fmaf(qq.x, qq.x, qsq))));
    }
    #pragma unroll
    for (int off = 32; off > 0; off >>= 1) {
        dot += __shfl_down(dot, off, 64);
        msq += __shfl_down(msq, off, 64);
        qsq += __shfl_down(qsq, off, 64);
    }
    if (lane == 0) {
        float denom = fmaxf(sqrtf(qsq) * sqrtf(msq), EPS);
        weighted[row] = (dot / denom) * imp[row] * expf(-0.001f * age[row]);
    }
}

// ---------------------------------------------------------------------------
// Kernel B (fused): redundant per-block top-k (register-resident candidates)
// + per-block mean of the k rows into LDS + decode of 4 outputs per block.
// 1024 blocks x 256 threads. Eliminates the former single-block (serial)
// topk_gather kernel, its launch gap, and the retrieved[] round-trip.
//
// Ownership: thread t owns elements {j*1024 + t*4 + c : j=0..7, c=0..3},
// loaded as 8 coalesced float4 (w4[j*256 + t]) kept in registers. Removal
// and rescan use only compile-time register indices (no scratch).
// Lowest-index tie-break on the GLOBAL index matches jax.lax.top_k.
// ---------------------------------------------------------------------------
__global__ __launch_bounds__(256) void topk_decode_kernel(
    const float* __restrict__ weighted,
    const float* __restrict__ mb,
    const int* __restrict__ topk_ptr,
    const float* __restrict__ W,
    const float* __restrict__ b,
    float* __restrict__ out)
{
    __shared__ float rbar[DIM];        // 16 KiB mean-pooled row
    __shared__ float rv[4];
    __shared__ int   ri[4];
    __shared__ int   sidx[64];

    const int tid  = threadIdx.x;
    const int wave = tid >> 6;
    const int lane = tid & 63;

    int k = *topk_ptr;
    if (k < 1) k = 1;
    if (k > 64) k = 64;

    // ---- load 32 candidates per thread into registers (coalesced) ----
    const float4* __restrict__ w4 = (const float4*)weighted;
    float4 val[8];
    #pragma unroll
    for (int j = 0; j < 8; ++j) val[j] = w4[(j << 8) + tid];

    // ---- initial per-thread argmax (ascending global index, strict >) ----
    float bv = -INFINITY; int bi = 0x7fffffff;
    #pragma unroll
    for (int j = 0; j < 8; ++j) {
        const int base = (j << 10) + (tid << 2);
        if (val[j].x > bv) { bv = val[j].x; bi = base + 0; }
        if (val[j].y > bv) { bv = val[j].y; bi = base + 1; }
        if (val[j].z > bv) { bv = val[j].z; bi = base + 2; }
        if (val[j].w > bv) { bv = val[j].w; bi = base + 3; }
    }

    for (int it = 0; it < k; ++it) {
        // wave shuffle argmax with global-index tie-break
        float cv = bv; int ci = bi;
        #pragma unroll
        for (int off = 32; off > 0; off >>= 1) {
            float ov = __shfl_down(cv, off, 64);
            int   oi = __shfl_down(ci, off, 64);
            if (ov > cv || (ov == cv && oi < ci)) { cv = ov; ci = oi; }
        }
        if (lane == 0) { rv[wave] = cv; ri[wave] = ci; }
        __syncthreads();
        if (tid == 0) {
            float best = rv[0]; int besti = ri[0];
            #pragma unroll
            for (int w = 1; w < 4; ++w) {
                if (rv[w] > best || (rv[w] == best && ri[w] < besti)) {
                    best = rv[w]; besti = ri[w];
                }
            }
            sidx[it] = besti;
        }
        __syncthreads();
        const int gbi = sidx[it];
        // owner removes the selected element and rescans its 32 registers
        if (((gbi >> 2) & 255) == tid) {
            const int jr = gbi >> 10;
            const int cr = gbi & 3;
            #pragma unroll
            for (int j = 0; j < 8; ++j) {
                if (j == jr) {
                    if (cr == 0) val[j].x = -INFINITY;
                    if (cr == 1) val[j].y = -INFINITY;
                    if (cr == 2) val[j].z = -INFINITY;
                    if (cr == 3) val[j].w = -INFINITY;
                }
            }
            bv = -INFINITY; bi = 0x7fffffff;
            #pragma unroll
            for (int j = 0; j < 8; ++j) {
                const int base = (j << 10) + (tid << 2);
                if (val[j].x > bv) { bv = val[j].x; bi = base + 0; }
                if (val[j].y > bv) { bv = val[j].y; bi = base + 1; }
                if (val[j].z > bv) { bv = val[j].z; bi = base + 2; }
                if (val[j].w > bv) { bv = val[j].w; bi = base + 3; }
            }
        }
        // wave lockstep orders the rescan before next iteration's shuffles;
        // cross-wave flow goes through rv/ri + __syncthreads.
    }
    __syncthreads();

    // ---- mean-pool the k selected rows into LDS (rows are L2-broadcast) ----
    const float inv_k = 1.0f / (float)k;
    float4* __restrict__ rbar4 = (float4*)rbar;
    for (int i = tid; i < DIM / 4; i += 256) {
        float4 acc = make_float4(0.f, 0.f, 0.f, 0.f);
        for (int r = 0; r < k; ++r) {
            const float4 v = ((const float4*)(mb + (size_t)sidx[r] * DIM))[i];
            acc.x += v.x; acc.y += v.y; acc.z += v.z; acc.w += v.w;
        }
        acc.x *= inv_k; acc.y *= inv_k; acc.z *= inv_k; acc.w *= inv_k;
        rbar4[i] = acc;
    }
    __syncthreads();

    // ---- decode: wave-per-output, 4 outputs per block ----
    const int j = (blockIdx.x << 2) + wave;
    const float4* __restrict__ wrow = (const float4*)(W + (size_t)j * DIM);

    float acc = 0.f;
    #pragma unroll 4
    for (int i = lane; i < DIM / 4; i += 64) {
        float4 w = wrow[i];
        float4 v = rbar4[i];
        acc = fmaf(w.w, v.w, fmaf(w.z, v.z, fmaf(w.y, v.y, fmaf(w.x, v.x, acc))));
    }
    #pragma unroll
    for (int off = 32; off > 0; off >>= 1) acc += __shfl_down(acc, off, 64);
    if (lane == 0) out[j] = acc + b[j];
}

extern "C" void kernel_launch(void* const* d_in, const int* in_sizes, int n_in,
                              void* d_out, int out_size, void* d_ws, size_t ws_size,
                              hipStream_t stream) {
    const float* query      = (const float*)d_in[0];
    const float* memory     = (const float*)d_in[1];
    const float* importance = (const float*)d_in[2];
    const float* age        = (const float*)d_in[3];
    const float* W_dec      = (const float*)d_in[4];
    const float* b_dec      = (const float*)d_in[5];
    const int*   top_k      = (const int*)d_in[6];

    float* weighted = (float*)d_ws;                  // CAP floats
    float* out      = (float*)d_out;

    score_kernel<<<CAP / 4, 256, 0, stream>>>(query, memory, importance, age, weighted);
    topk_decode_kernel<<<DIM / 4, 256, 0, stream>>>(weighted, memory, top_k,
                                                    W_dec, b_dec, out);
}